// Round 2
// baseline (569.873 us; speedup 1.0000x reference)
//
#include <hip/hip_runtime.h>
#include <hip/hip_bf16.h>
#include <stdint.h>

// INT4Linear: out[m,o] = sum_k x[m,k] * W[o,k]*scale + bias[o]
// M=8192, N=4096, K=4096.
// Device dtypes (revised theory): x/scale/bias/out = float32 (fp16 upcast by
// harness; "else float*" clause), weight_int4 = int32 (sign-extended packed byte).
// GEMM computed in bf16 MFMA (tolerance 1.86 allows bf16-grade rounding).
// Tiered on ws_size:
//   tier 0 (ws >= 100.7 MB): x->bf16 and W->bf16 in ws, pure m97 gload_lds GEMM
//   tier 1 (ws >=  33.6 MB): W->bf16 in ws; A reg-staged fp32->bf16
//   tier 2 (fallback): fully fused (A fp32->bf16, B int4->bf16 in staging)

typedef __bf16 bf16;
typedef __bf16 bf16x8 __attribute__((ext_vector_type(8)));
typedef float  f32x4  __attribute__((ext_vector_type(4)));

constexpr int M_DIM = 8192;
constexpr int N_DIM = 4096;
constexpr int K_DIM = 4096;
constexpr int KB    = K_DIM / 2;   // packed bytes (one per int) per output row

constexpr int BM = 128;
constexpr int BN = 128;
constexpr int BK = 64;

__device__ __forceinline__ void gload_lds16(const void* g, void* l) {
  __builtin_amdgcn_global_load_lds(
      (const __attribute__((address_space(1))) void*)g,
      (__attribute__((address_space(3))) void*)l,
      16, 0, 0);
}

// robust to both int8->int32 widening conventions (sign-extended or zero-padded)
__device__ __forceinline__ float dq_hi_f(int b) {
  int sb = (int)(signed char)(b & 0xFF);
  return (float)(sb >> 4);
}
__device__ __forceinline__ float dq_lo_f(int b) {
  int sb = (int)(signed char)(b & 0xFF);
  return (float)(((sb & 15) ^ 8) - 8);
}

// ---------------- x: fp32 -> bf16 ----------------
__global__ void convert_x(const float* __restrict__ x, bf16* __restrict__ xc) {
  const size_t i = (size_t)blockIdx.x * 256 + threadIdx.x;
  const float4 a = ((const float4*)x)[2 * i];
  const float4 b = ((const float4*)x)[2 * i + 1];
  bf16x8 o;
  o[0] = (bf16)a.x; o[1] = (bf16)a.y; o[2] = (bf16)a.z; o[3] = (bf16)a.w;
  o[4] = (bf16)b.x; o[5] = (bf16)b.y; o[6] = (bf16)b.z; o[7] = (bf16)b.w;
  *(bf16x8*)(xc + i * 8) = o;
}

// ---------------- W: packed int4 (one byte per int32) -> bf16 [N][K] ----------------
__global__ void dequant_w(const int* __restrict__ wq, bf16* __restrict__ W,
                          const float* __restrict__ scale_p) {
  const float s = scale_p[0];
  const size_t idx = (size_t)blockIdx.x * 256 + threadIdx.x;  // one int4 = 4 packed bytes
  const int4 v = ((const int4*)wq)[idx];
  bf16x8 o;
  o[0] = (bf16)(dq_hi_f(v.x) * s); o[1] = (bf16)(dq_lo_f(v.x) * s);
  o[2] = (bf16)(dq_hi_f(v.y) * s); o[3] = (bf16)(dq_lo_f(v.y) * s);
  o[4] = (bf16)(dq_hi_f(v.z) * s); o[5] = (bf16)(dq_lo_f(v.z) * s);
  o[6] = (bf16)(dq_hi_f(v.w) * s); o[7] = (bf16)(dq_lo_f(v.w) * s);
  *(bf16x8*)(W + idx * 8) = o;
}

// ---------------- GEMM: C[M,N] = A[M,K] * W[N,K]^T + bias ----------------
template <int MODE>   // 0: A,B gload_lds (bf16 srcs); 1: A reg-staged, B gload_lds; 2: fused
__global__ void __launch_bounds__(256)
gemm_bt(const float* __restrict__ Xf, const bf16* __restrict__ Xc,
        const bf16* __restrict__ W,  const int* __restrict__ WQ,
        const float* __restrict__ scale_p, const float* __restrict__ bias,
        float* __restrict__ out) {
  __shared__ __align__(16) bf16 As[BM][BK];
  __shared__ __align__(16) bf16 Bs[BN][BK];

  const int tid = threadIdx.x;
  const int w   = tid >> 6;
  const int l   = tid & 63;

  // bijective XCD swizzle (nwg = 2048, divisible by 8)
  const int nwg = gridDim.x;
  const int cpx = nwg >> 3;
  const int bid = blockIdx.x;
  const int wg  = (bid & 7) * cpx + (bid >> 3);

  const int ntN = N_DIM / BN;   // 32
  const int m0  = (wg / ntN) * BM;
  const int n0  = (wg % ntN) * BN;

  const int wm = w >> 1, wn = w & 1;       // 2x2 wave grid, each wave 64x64
  const int lrow = l & 15, lg = l >> 4;

  f32x4 acc[4][4] = {};

  const float s = (MODE == 2) ? scale_p[0] : 0.0f;

  // gload_lds staging geometry (modes 0/1): lane l of wave w covers
  // row w*8 + l/8 (+i*32), col (l%8)*8 — matches HW's base + lane*16B layout.
  const int arow = (w << 3) + (l >> 3);
  const int acol = (l & 7) << 3;
  // reg-staging geometry (modes 1/2): thread covers row tid/2, 32 cols at (tid&1)*32
  const int rr = tid >> 1, rh = tid & 1;

  for (int k0 = 0; k0 < K_DIM; k0 += BK) {
    // ---- stage A tile ----
    if constexpr (MODE == 0) {
      const bf16* gA = Xc + (size_t)(m0 + arow) * K_DIM + (k0 + acol);
#pragma unroll
      for (int i = 0; i < 4; ++i)
        gload_lds16(gA + (size_t)(i * 32) * K_DIM, &As[i * 32 + (w << 3)][0]);
    } else {
      const float* gx = Xf + (size_t)(m0 + rr) * K_DIM + k0 + rh * 32;
      float4 xa[8];
#pragma unroll
      for (int u = 0; u < 8; ++u) xa[u] = ((const float4*)gx)[u];
      bf16* dst = &As[rr][rh * 32];
#pragma unroll
      for (int u = 0; u < 4; ++u) {
        const float4 p = xa[2 * u], q = xa[2 * u + 1];
        bf16x8 o;
        o[0] = (bf16)p.x; o[1] = (bf16)p.y; o[2] = (bf16)p.z; o[3] = (bf16)p.w;
        o[4] = (bf16)q.x; o[5] = (bf16)q.y; o[6] = (bf16)q.z; o[7] = (bf16)q.w;
        *(bf16x8*)(dst + u * 8) = o;
      }
    }

    // ---- stage B tile ----
    if constexpr (MODE <= 1) {
      const bf16* gB = W + (size_t)(n0 + arow) * K_DIM + (k0 + acol);
#pragma unroll
      for (int i = 0; i < 4; ++i)
        gload_lds16(gB + (size_t)(i * 32) * K_DIM, &Bs[i * 32 + (w << 3)][0]);
    } else {
      const int4* gq = (const int4*)(WQ + (size_t)(n0 + rr) * KB + (k0 >> 1) + rh * 16);
      const int4 q0 = gq[0], q1 = gq[1], q2 = gq[2], q3 = gq[3];
      const int vals[16] = {q0.x, q0.y, q0.z, q0.w, q1.x, q1.y, q1.z, q1.w,
                            q2.x, q2.y, q2.z, q2.w, q3.x, q3.y, q3.z, q3.w};
      bf16* dst = &Bs[rr][rh * 32];
#pragma unroll
      for (int u = 0; u < 4; ++u) {
        bf16x8 ov;
#pragma unroll
        for (int e = 0; e < 4; ++e) {
          const int b = vals[u * 4 + e];
          ov[e * 2]     = (bf16)(dq_hi_f(b) * s);
          ov[e * 2 + 1] = (bf16)(dq_lo_f(b) * s);
        }
        *(bf16x8*)(dst + u * 8) = ov;
      }
    }

    __syncthreads();

    // ---- compute: 2 k-substeps of 32, 16 MFMA each ----
#pragma unroll
    for (int kk = 0; kk < BK; kk += 32) {
      bf16x8 af[4], bfr[4];
#pragma unroll
      for (int i = 0; i < 4; ++i)
        af[i] = *(const bf16x8*)&As[wm * 64 + i * 16 + lrow][kk + lg * 8];
#pragma unroll
      for (int j = 0; j < 4; ++j)
        bfr[j] = *(const bf16x8*)&Bs[wn * 64 + j * 16 + lrow][kk + lg * 8];
#pragma unroll
      for (int i = 0; i < 4; ++i)
#pragma unroll
        for (int j = 0; j < 4; ++j)
          acc[i][j] = __builtin_amdgcn_mfma_f32_16x16x32_bf16(af[i], bfr[j],
                                                              acc[i][j], 0, 0, 0);
    }

    __syncthreads();
  }

  // ---- epilogue: +bias, fp32 store ----
  float bv[4];
#pragma unroll
  for (int j = 0; j < 4; ++j)
    bv[j] = bias[n0 + wn * 64 + j * 16 + lrow];

#pragma unroll
  for (int i = 0; i < 4; ++i) {
#pragma unroll
    for (int r = 0; r < 4; ++r) {
      const size_t grow = (size_t)m0 + wm * 64 + i * 16 + lg * 4 + r;
      float* orow = out + grow * N_DIM + (n0 + wn * 64 + lrow);
#pragma unroll
      for (int j = 0; j < 4; ++j)
        orow[j * 16] = acc[i][j][r] + bv[j];
    }
  }
}

extern "C" void kernel_launch(void* const* d_in, const int* in_sizes, int n_in,
                              void* d_out, int out_size, void* d_ws, size_t ws_size,
                              hipStream_t stream) {
  const float* x     = (const float*)d_in[0];
  const int*   wq    = (const int*)d_in[1];
  const float* scale = (const float*)d_in[2];
  const float* bias  = (const float*)d_in[3];
  float*       out   = (float*)d_out;

  const size_t wb = (size_t)N_DIM * K_DIM * sizeof(bf16);   // 33.55 MB
  const size_t xb = (size_t)M_DIM * K_DIM * sizeof(bf16);   // 67.11 MB
  bf16* Wd = (bf16*)d_ws;
  bf16* Xc = (bf16*)((char*)d_ws + wb);

  const dim3 grid((M_DIM / BM) * (N_DIM / BN));  // 2048 blocks

  if (ws_size >= wb + xb) {
    dequant_w<<<(N_DIM * KB / 4) / 256, 256, 0, stream>>>(wq, Wd, scale);
    convert_x<<<((size_t)M_DIM * K_DIM / 8) / 256, 256, 0, stream>>>(x, Xc);
    gemm_bt<0><<<grid, 256, 0, stream>>>(nullptr, Xc, Wd, nullptr, scale, bias, out);
  } else if (ws_size >= wb) {
    dequant_w<<<(N_DIM * KB / 4) / 256, 256, 0, stream>>>(wq, Wd, scale);
    gemm_bt<1><<<grid, 256, 0, stream>>>(x, nullptr, Wd, nullptr, scale, bias, out);
  } else {
    gemm_bt<2><<<grid, 256, 0, stream>>>(x, nullptr, nullptr, wq, scale, bias, out);
  }
}

// Round 3
// 533.819 us; speedup vs baseline: 1.0675x; 1.0675x over previous
//
#include <hip/hip_runtime.h>
#include <hip/hip_bf16.h>
#include <stdint.h>

// INT4Linear: out[m,o] = sum_k x[m,k]*W[o,k]*scale + bias[o]
// M=8192, N=4096, K=4096. x/scale/bias/out = fp32 on device; weight = int32
// (one sign-extended packed byte each). Pipeline:
//   1) convert_x: fp32 -> bf16 (67MB in ws)
//   2) dequant_w: int4 -> bf16 W[N][K] (32MB in ws)
//   3) gemm8p: 256x256x64 8-wave 4-phase/K-tile MFMA GEMM with
//      T2 LDS swizzle + T3/T4 counted-vmcnt pipeline + T5 setprio.

typedef __bf16 bf16;
typedef __bf16 bf16x8 __attribute__((ext_vector_type(8)));
typedef float  f32x4  __attribute__((ext_vector_type(4)));

constexpr int M_DIM = 8192;
constexpr int N_DIM = 4096;
constexpr int K_DIM = 4096;
constexpr int KB    = K_DIM / 2;

constexpr int BM = 256;
constexpr int BN = 256;
constexpr int BK = 64;
constexpr int NKT = K_DIM / BK;   // 64 K-tiles

__device__ __forceinline__ void gload_lds16(const void* g, void* l) {
  __builtin_amdgcn_global_load_lds(
      (const __attribute__((address_space(1))) void*)g,
      (__attribute__((address_space(3))) void*)l,
      16, 0, 0);
}

__device__ __forceinline__ void fence_barrier() {
  asm volatile("" ::: "memory");
  __builtin_amdgcn_s_barrier();
  asm volatile("" ::: "memory");
}

__device__ __forceinline__ float dq_hi_f(int b) {
  int sb = (int)(signed char)(b & 0xFF);
  return (float)(sb >> 4);
}
__device__ __forceinline__ float dq_lo_f(int b) {
  int sb = (int)(signed char)(b & 0xFF);
  return (float)(((sb & 15) ^ 8) - 8);
}

// ---------------- x: fp32 -> bf16 ----------------
__global__ void convert_x(const float* __restrict__ x, bf16* __restrict__ xc) {
  const size_t i = (size_t)blockIdx.x * 256 + threadIdx.x;
  const float4 a = ((const float4*)x)[2 * i];
  const float4 b = ((const float4*)x)[2 * i + 1];
  bf16x8 o;
  o[0] = (bf16)a.x; o[1] = (bf16)a.y; o[2] = (bf16)a.z; o[3] = (bf16)a.w;
  o[4] = (bf16)b.x; o[5] = (bf16)b.y; o[6] = (bf16)b.z; o[7] = (bf16)b.w;
  *(bf16x8*)(xc + i * 8) = o;
}

// ---------------- W: packed int4 -> bf16 [N][K] ----------------
__global__ void dequant_w(const int* __restrict__ wq, bf16* __restrict__ W,
                          const float* __restrict__ scale_p) {
  const float s = scale_p[0];
  const size_t idx = (size_t)blockIdx.x * 256 + threadIdx.x;
  const int4 v = ((const int4*)wq)[idx];
  bf16x8 o;
  o[0] = (bf16)(dq_hi_f(v.x) * s); o[1] = (bf16)(dq_lo_f(v.x) * s);
  o[2] = (bf16)(dq_hi_f(v.y) * s); o[3] = (bf16)(dq_lo_f(v.y) * s);
  o[4] = (bf16)(dq_hi_f(v.z) * s); o[5] = (bf16)(dq_lo_f(v.z) * s);
  o[6] = (bf16)(dq_hi_f(v.w) * s); o[7] = (bf16)(dq_lo_f(v.w) * s);
  *(bf16x8*)(W + idx * 8) = o;
}

// ---------------- 8-phase-style 256x256 GEMM ----------------
// 512 threads = 8 waves (2 M x 4 N), per-wave output 128x64.
// LDS: double-buffered A[256][64] + B[256][64] bf16 = 128 KiB.
// Swizzle (involution, both sides): element col ^= (row&7)<<3.
//   write side: gload_lds lane l covers subtile row l>>3, col (l&7)*8
//               -> pre-swizzled global col = ((l&7)^(l>>3))*8
//   read  side: &T[row][col ^ ((row&7)<<3)]
// Schedule per K-tile kt (buf = kt&1), 4 phases:
//   q1: stage B0(kt+1) | read A-ksub0(8) B-ksub0(4) | bar | lgkm0 | 16 MFMA (mh0,ks0) | bar
//   q2: stage B1(kt+1) | read A-ksub1(8) B-ksub1(4) | bar | lgkm0 | 16 MFMA (mh1,ks0) | bar
//   q3: stage A0(kt+2) |                              bar |         16 MFMA (mh0,ks1) | bar
//   q4: stage A1(kt+2) |                                            16 MFMA (mh1,ks1) | vmcnt(4) | bar
// Race-freedom: all reads of buf complete by q2's lgkmcnt(0)+barrier, so
// q3/q4 may stage kt+2 into the SAME buffer. vmcnt(4) leaves only the newest
// 2 half-tiles (A of kt+2) in flight -> kt+1 fully arrived. Tail: vmcnt(0).

#define MMA16(AF, BF, ACCOFF)                                                  \
  {                                                                            \
    _Pragma("unroll") for (int i_ = 0; i_ < 4; ++i_) {                         \
      _Pragma("unroll") for (int j_ = 0; j_ < 4; ++j_) {                       \
        acc[(ACCOFF) + i_][j_] = __builtin_amdgcn_mfma_f32_16x16x32_bf16(      \
            (AF)[i_], (BF)[j_], acc[(ACCOFF) + i_][j_], 0, 0, 0);              \
      }                                                                        \
    }                                                                          \
  }

__global__ void __launch_bounds__(512, 2)
gemm8p(const bf16* __restrict__ Xc, const bf16* __restrict__ W,
       const float* __restrict__ bias, float* __restrict__ out) {
  __shared__ __align__(16) bf16 As[2][BM][BK];
  __shared__ __align__(16) bf16 Bs[2][BN][BK];

  const int tid = threadIdx.x;
  const int w   = tid >> 6;       // wave 0..7
  const int l   = tid & 63;
  const int wm  = w >> 2;         // 0..1 (M half)
  const int wn  = w & 3;          // 0..3 (N quarter)
  const int lrow = l & 15, lg = l >> 4;

  // bijective XCD swizzle: 512 wgs, 512%8==0
  const int bid = blockIdx.x;
  const int wg  = (bid & 7) * 64 + (bid >> 3);
  const int m0  = (wg >> 4) * BM;   // 32 M-tiles
  const int n0  = (wg & 15) * BN;   // 16 N-tiles

  // staging lane geometry (pre-swizzled source)
  const int srow = l >> 3;                      // row within 8-row subtile
  const int scol = ((l & 7) ^ srow) << 3;       // swizzled global col (elements)
  const bf16* gA = Xc + (size_t)(m0 + w * 16 + srow) * K_DIM + scol;
  const bf16* gB = W  + (size_t)(n0 + w * 16 + srow) * K_DIM + scol;

  const int rsw = (lrow & 7) << 3;              // read-side col XOR (elements)

  f32x4 acc[8][4] = {};

#define STAGE_A(KT, H)                                                         \
  {                                                                            \
    gload_lds16(gA + (size_t)((H) * 128) * K_DIM + (KT) * BK,                  \
                &As[(KT) & 1][(H) * 128 + w * 16][0]);                         \
    gload_lds16(gA + (size_t)((H) * 128 + 8) * K_DIM + (KT) * BK,              \
                &As[(KT) & 1][(H) * 128 + w * 16 + 8][0]);                     \
  }
#define STAGE_B(KT, H)                                                         \
  {                                                                            \
    gload_lds16(gB + (size_t)((H) * 128) * K_DIM + (KT) * BK,                  \
                &Bs[(KT) & 1][(H) * 128 + w * 16][0]);                         \
    gload_lds16(gB + (size_t)((H) * 128 + 8) * K_DIM + (KT) * BK,              \
                &Bs[(KT) & 1][(H) * 128 + w * 16 + 8][0]);                     \
  }

  // ---- prologue: K-tile 0 (4 halves) + A halves of K-tile 1 ----
  STAGE_A(0, 0); STAGE_A(0, 1); STAGE_B(0, 0); STAGE_B(0, 1);
  STAGE_A(1, 0); STAGE_A(1, 1);
  asm volatile("s_waitcnt vmcnt(4)" ::: "memory");  // K-tile 0 arrived
  fence_barrier();

  for (int kt = 0; kt < NKT; ++kt) {
    const int buf = kt & 1;
    bf16x8 a0[8], a1[8], b0[4], b1[4];

    // ---------- q1 ----------
    if (kt + 1 < NKT) STAGE_B(kt + 1, 0);
#pragma unroll
    for (int i = 0; i < 8; ++i)
      a0[i] = *(const bf16x8*)&As[buf][wm * 128 + i * 16 + lrow][(lg * 8) ^ rsw];
#pragma unroll
    for (int j = 0; j < 4; ++j)
      b0[j] = *(const bf16x8*)&Bs[buf][wn * 64 + j * 16 + lrow][(lg * 8) ^ rsw];
    fence_barrier();
    asm volatile("s_waitcnt lgkmcnt(0)" ::: "memory");
    __builtin_amdgcn_s_setprio(1);
    MMA16(a0, b0, 0);
    __builtin_amdgcn_s_setprio(0);
    fence_barrier();

    // ---------- q2 ----------
    if (kt + 1 < NKT) STAGE_B(kt + 1, 1);
#pragma unroll
    for (int i = 0; i < 8; ++i)
      a1[i] = *(const bf16x8*)&As[buf][wm * 128 + i * 16 + lrow][(32 + lg * 8) ^ rsw];
#pragma unroll
    for (int j = 0; j < 4; ++j)
      b1[j] = *(const bf16x8*)&Bs[buf][wn * 64 + j * 16 + lrow][(32 + lg * 8) ^ rsw];
    fence_barrier();
    asm volatile("s_waitcnt lgkmcnt(0)" ::: "memory");  // ALL reads of buf done
    __builtin_amdgcn_s_setprio(1);
    MMA16(a0 + 4, b0, 4);
    __builtin_amdgcn_s_setprio(0);
    fence_barrier();

    // ---------- q3 (buf's reads are all done -> safe to stage kt+2 here) ----
    if (kt + 2 < NKT) STAGE_A(kt + 2, 0);
    fence_barrier();
    __builtin_amdgcn_s_setprio(1);
    MMA16(a1, b1, 0);
    __builtin_amdgcn_s_setprio(0);
    fence_barrier();

    // ---------- q4 ----------
    if (kt + 2 < NKT) STAGE_A(kt + 2, 1);
    __builtin_amdgcn_s_setprio(1);
    MMA16(a1 + 4, b1, 4);
    __builtin_amdgcn_s_setprio(0);
    if (kt + 2 < NKT) {
      asm volatile("s_waitcnt vmcnt(4)" ::: "memory");  // kt+1 fully arrived
    } else {
      asm volatile("s_waitcnt vmcnt(0)" ::: "memory");  // tail drain
    }
    fence_barrier();
  }

  // ---- epilogue: +bias, fp32 store ----
  float bv[4];
#pragma unroll
  for (int j = 0; j < 4; ++j) bv[j] = bias[n0 + wn * 64 + j * 16 + lrow];

#pragma unroll
  for (int i = 0; i < 8; ++i) {
#pragma unroll
    for (int r = 0; r < 4; ++r) {
      float* orow = out + (size_t)(m0 + wm * 128 + i * 16 + lg * 4 + r) * N_DIM
                        + (n0 + wn * 64 + lrow);
#pragma unroll
      for (int j = 0; j < 4; ++j) orow[j * 16] = acc[i][j][r] + bv[j];
    }
  }
}

// ---------------- fallback (ws too small): fused simple GEMM ----------------
__global__ void __launch_bounds__(256)
gemm_fused(const float* __restrict__ Xf, const int* __restrict__ WQ,
           const float* __restrict__ scale_p, const float* __restrict__ bias,
           float* __restrict__ out) {
  __shared__ __align__(16) bf16 As[128][64];
  __shared__ __align__(16) bf16 Bs[128][64];
  const int tid = threadIdx.x;
  const int w = tid >> 6, l = tid & 63;
  const int nwg = gridDim.x, cpx = nwg >> 3, bid = blockIdx.x;
  const int wg = (bid & 7) * cpx + (bid >> 3);
  const int ntN = N_DIM / 128;
  const int m0 = (wg / ntN) * 128, n0 = (wg % ntN) * 128;
  const int wm = w >> 1, wn = w & 1;
  const int lrow = l & 15, lg = l >> 4;
  f32x4 acc[4][4] = {};
  const float s = scale_p[0];
  const int rr = tid >> 1, rh = tid & 1;
  for (int k0 = 0; k0 < K_DIM; k0 += 64) {
    const float* gx = Xf + (size_t)(m0 + rr) * K_DIM + k0 + rh * 32;
    float4 xa[8];
#pragma unroll
    for (int u = 0; u < 8; ++u) xa[u] = ((const float4*)gx)[u];
    bf16* dst = &As[rr][rh * 32];
#pragma unroll
    for (int u = 0; u < 4; ++u) {
      const float4 p = xa[2 * u], q = xa[2 * u + 1];
      bf16x8 o;
      o[0] = (bf16)p.x; o[1] = (bf16)p.y; o[2] = (bf16)p.z; o[3] = (bf16)p.w;
      o[4] = (bf16)q.x; o[5] = (bf16)q.y; o[6] = (bf16)q.z; o[7] = (bf16)q.w;
      *(bf16x8*)(dst + u * 8) = o;
    }
    const int4* gq = (const int4*)(WQ + (size_t)(n0 + rr) * KB + (k0 >> 1) + rh * 16);
    const int4 q0 = gq[0], q1 = gq[1], q2 = gq[2], q3 = gq[3];
    const int vals[16] = {q0.x, q0.y, q0.z, q0.w, q1.x, q1.y, q1.z, q1.w,
                          q2.x, q2.y, q2.z, q2.w, q3.x, q3.y, q3.z, q3.w};
    bf16* bdst = &Bs[rr][rh * 32];
#pragma unroll
    for (int u = 0; u < 4; ++u) {
      bf16x8 ov;
#pragma unroll
      for (int e = 0; e < 4; ++e) {
        const int b = vals[u * 4 + e];
        ov[e * 2]     = (bf16)(dq_hi_f(b) * s);
        ov[e * 2 + 1] = (bf16)(dq_lo_f(b) * s);
      }
      *(bf16x8*)(bdst + u * 8) = ov;
    }
    __syncthreads();
#pragma unroll
    for (int kk = 0; kk < 64; kk += 32) {
      bf16x8 af[4], bfr[4];
#pragma unroll
      for (int i = 0; i < 4; ++i)
        af[i] = *(const bf16x8*)&As[wm * 64 + i * 16 + lrow][kk + lg * 8];
#pragma unroll
      for (int j = 0; j < 4; ++j)
        bfr[j] = *(const bf16x8*)&Bs[wn * 64 + j * 16 + lrow][kk + lg * 8];
#pragma unroll
      for (int i = 0; i < 4; ++i)
#pragma unroll
        for (int j = 0; j < 4; ++j)
          acc[i][j] = __builtin_amdgcn_mfma_f32_16x16x32_bf16(af[i], bfr[j],
                                                              acc[i][j], 0, 0, 0);
    }
    __syncthreads();
  }
  float bv[4];
#pragma unroll
  for (int j = 0; j < 4; ++j) bv[j] = bias[n0 + wn * 64 + j * 16 + lrow];
#pragma unroll
  for (int i = 0; i < 4; ++i)
#pragma unroll
    for (int r = 0; r < 4; ++r) {
      float* orow = out + (size_t)(m0 + wm * 64 + i * 16 + lg * 4 + r) * N_DIM
                        + (n0 + wn * 64 + lrow);
#pragma unroll
      for (int j = 0; j < 4; ++j) orow[j * 16] = acc[i][j][r] + bv[j];
    }
}

extern "C" void kernel_launch(void* const* d_in, const int* in_sizes, int n_in,
                              void* d_out, int out_size, void* d_ws, size_t ws_size,
                              hipStream_t stream) {
  const float* x     = (const float*)d_in[0];
  const int*   wq    = (const int*)d_in[1];
  const float* scale = (const float*)d_in[2];
  const float* bias  = (const float*)d_in[3];
  float*       out   = (float*)d_out;

  const size_t wb = (size_t)N_DIM * K_DIM * sizeof(bf16);   // 33.55 MB
  const size_t xb = (size_t)M_DIM * K_DIM * sizeof(bf16);   // 67.11 MB

  if (ws_size >= wb + xb) {
    bf16* Wd = (bf16*)d_ws;
    bf16* Xc = (bf16*)((char*)d_ws + wb);
    dequant_w<<<(N_DIM * KB / 4) / 256, 256, 0, stream>>>(wq, Wd, scale);
    convert_x<<<((size_t)M_DIM * K_DIM / 8) / 256, 256, 0, stream>>>(x, Xc);
    gemm8p<<<dim3((M_DIM / BM) * (N_DIM / BN)), 512, 0, stream>>>(Xc, Wd, bias, out);
  } else {
    gemm_fused<<<dim3((M_DIM / 128) * (N_DIM / 128)), 256, 0, stream>>>(
        x, wq, scale, bias, out);
  }
}